// Round 1
// baseline (208.568 us; speedup 1.0000x reference)
//
#include <hip/hip_runtime.h>

#define BB 16
#define HH 512
#define WW 512
#define BH 16
#define NBANDS (HH/BH)
#define NREG 48
#define HWTOT (HH*WW)

// ws layout (bytes):
//   0       double sums[48][12]   (sumP[3], sumP2[3], sdx[3], sdy[3])
//   4608    double sumAbs
//   4616    int counts[48][9]     (cnt[3], cx[3], cy[3])
//   6344    float rankval[48]
//   6536    int rankvalid[48]
//   8192    u64 maskReg[48][512][8]
//   1581056 u64 maskE1 [48][512][8]
#define OFF_SUMABS 4608
#define OFF_COUNTS 4616
#define OFF_RANKV  6344
#define OFF_RANKD  6536
#define OFF_MREG   8192
#define MASKBYTES  (48LL*512*8*8)
#define OFF_ME1    (OFF_MREG + MASKBYTES)

__device__ __forceinline__ unsigned int hashu(unsigned int x) {
  x ^= x >> 16; x *= 0x7feb352dU; x ^= x >> 15; x *= 0x846ca68bU; x ^= x >> 16;
  return x;
}

__global__ __launch_bounds__(256) void pass1_kernel(
    const float* __restrict__ pred, const float* __restrict__ target,
    const int* __restrict__ lab,
    double* __restrict__ sums, double* __restrict__ sumAbs,
    int* __restrict__ counts,
    unsigned long long* __restrict__ mRegG, unsigned long long* __restrict__ mE1G)
{
  __shared__ unsigned long long REG[3][BH+5][8];
  __shared__ unsigned long long E1v[3][BH+5][8];
  __shared__ unsigned long long E2v[3][BH+5][8];
  __shared__ unsigned long long Hh[BH+5][8];
  __shared__ unsigned long long E1H[BH+5][8];
  __shared__ float PF[WW];

  const int t    = threadIdx.x;
  const int lane = t & 63;
  const int wv   = t >> 6;
  const int r0   = blockIdx.x * BH;
  const int b    = blockIdx.y;
  const int R    = r0 - 3;

  // ---- build region bitmasks for rows lr 0..BH+4 (gy = R+lr) ----
  for (int lr = 0; lr < BH+5; ++lr) {
    int gy = R + lr;
    int l1 = -1, l2 = -1;
    if ((unsigned)gy < (unsigned)HH) {
      const int* lp = lab + ((size_t)b*HH + gy)*WW;
      l1 = lp[t]; l2 = lp[t+256];
    }
    {
      unsigned long long m1, m2;
      m1 = __ballot(l1 == 5);  m2 = __ballot(l2 == 5);
      if (lane == 0) { REG[0][lr][wv] = m1; REG[0][lr][wv+4] = m2; }
      m1 = __ballot(l1 == 8);  m2 = __ballot(l2 == 8);
      if (lane == 0) { REG[1][lr][wv] = m1; REG[1][lr][wv+4] = m2; }
      m1 = __ballot(l1 == 13); m2 = __ballot(l2 == 13);
      if (lane == 0) { REG[2][lr][wv] = m1; REG[2][lr][wv+4] = m2; }
    }
  }
  __syncthreads();

  // ---- erosions (clipped SAME boundary: out-of-bounds = skipped) ----
  for (int li = 0; li < 3; ++li) {
    for (int task = t; task < (BH+5)*8; task += 256) {
      int lr = task >> 3, w = task & 7;
      unsigned long long m  = REG[li][lr][w];
      unsigned long long lm = (m << 1) | (w ? (REG[li][lr][w-1] >> 63) : 1ULL);
      unsigned long long rm = (m >> 1) | ((w < 7) ? (REG[li][lr][w+1] << 63) : (1ULL << 63));
      Hh[lr][w] = m & lm & rm;
    }
    __syncthreads();
    for (int task = t; task < (BH+3)*8; task += 256) {
      int lr = (task >> 3) + 1, w = task & 7;
      int gy = R + lr;
      unsigned long long v = Hh[lr][w];
      if (gy - 1 >= 0) v &= Hh[lr-1][w];
      if (gy + 1 < HH) v &= Hh[lr+1][w];
      E1v[li][lr][w] = v;
    }
    __syncthreads();
    for (int task = t; task < (BH+3)*8; task += 256) {
      int lr = (task >> 3) + 1, w = task & 7;
      unsigned long long m  = E1v[li][lr][w];
      unsigned long long lm = (m << 1) | (w ? (E1v[li][lr][w-1] >> 63) : 1ULL);
      unsigned long long rm = (m >> 1) | ((w < 7) ? (E1v[li][lr][w+1] << 63) : (1ULL << 63));
      E1H[lr][w] = m & lm & rm;
    }
    __syncthreads();
    for (int task = t; task < (BH+1)*8; task += 256) {
      int lr = (task >> 3) + 2, w = task & 7;
      int gy = R + lr;
      unsigned long long v = E1H[lr][w];
      if (gy - 1 >= 0) v &= E1H[lr-1][w];
      if (gy + 1 < HH) v &= E1H[lr+1][w];
      E2v[li][lr][w] = v;
    }
    __syncthreads();
  }

  // ---- write region/e1 row masks for rank sampling (rows r0..r0+BH-1) ----
  for (int task = t; task < 3*BH*8; task += 256) {
    int w   = task & 7;
    int row = (task >> 3) & (BH - 1);
    int li  = task >> 7;
    int gy  = r0 + row;
    int lr  = row + 3;
    size_t base = (((size_t)(b*3 + li))*HH + gy)*8 + w;
    mRegG[base] = REG[li][lr][w];
    mE1G[base]  = E1v[li][lr][w];
  }

  // ---- counts: cnt, cx (horizontal pairs), cy (vertical pairs (gy-1,gy)) ----
  #pragma unroll
  for (int li = 0; li < 3; ++li) {
    #pragma unroll
    for (int m = 0; m < 3; ++m) {
      const unsigned long long (*M)[8] = (m == 0) ? REG[li] : ((m == 1) ? E1v[li] : E2v[li]);
      int c = 0, cx = 0, cy = 0;
      if (t < BH*8) {
        int row = t >> 3, w = t & 7;
        int lr = row + 3, gy = r0 + row;
        unsigned long long mm = M[lr][w];
        c = __popcll(mm);
        unsigned long long nx = (w < 7) ? M[lr][w+1] : 0ULL;
        unsigned long long pm = mm & ((mm >> 1) | (nx << 63));
        cx = __popcll(pm);
        cy = (gy > 0) ? __popcll(mm & M[lr-1][w]) : 0;
      }
      for (int off = 32; off; off >>= 1) {
        c  += __shfl_down(c, off);
        cx += __shfl_down(cx, off);
        cy += __shfl_down(cy, off);
      }
      if (lane == 0 && wv < 2) {
        int* C = counts + (b*3 + li)*9;
        atomicAdd(C + m,     c);
        atomicAdd(C + 3 + m, cx);
        atomicAdd(C + 6 + m, cy);
      }
    }
  }

  // ---- stats: per-thread accumulators over 2 columns (t, t+256) ----
  float aP[3][3]  = {};
  float aP2[3][3] = {};
  float aDX[3][3] = {};
  float aDY[3][3] = {};
  float aAbs = 0.f;

  float p1_prev = 0.f, p2_prev = 0.f;
  if (r0 > 0) {
    const float* pr = pred + ((size_t)b*HH + (r0-1))*WW;
    p1_prev = pr[t]; p2_prev = pr[t+256];
  }
  const int w1 = wv;
  const int b1 = lane;

  for (int row = 0; row < BH; ++row) {
    int gy = r0 + row;
    int lr = row + 3;
    const float* prow = pred   + ((size_t)b*HH + gy)*WW;
    const float* trow = target + ((size_t)b*HH + gy)*WW;
    float p1 = prow[t], p2 = prow[t+256];
    float tg1 = trow[t], tg2 = trow[t+256];
    aAbs += fabsf(p1 - tg1) + fabsf(p2 - tg2);
    PF[t] = p1; PF[t+256] = p2;
    __syncthreads();
    float pr1 = PF[t+1];
    float pr2 = (t < 255) ? PF[t+257] : 0.f;
    float d1  = fabsf(pr1 - p1);
    float d2  = fabsf(pr2 - p2);
    float v1  = fabsf(p1 - p1_prev);
    float v2  = fabsf(p2 - p2_prev);
    float p1s = p1*p1, p2s = p2*p2;
    bool hasUp = (gy > 0);
    bool hasR2 = (t < 255);
    #pragma unroll
    for (int li = 0; li < 3; ++li) {
      #pragma unroll
      for (int m = 0; m < 3; ++m) {
        const unsigned long long (*M)[8] = (m == 0) ? REG[li] : ((m == 1) ? E1v[li] : E2v[li]);
        unsigned long long cur1 = M[lr][w1];
        unsigned long long cur2 = M[lr][w1+4];
        unsigned int c1 = (unsigned int)(cur1 >> b1) & 1u;
        unsigned int c2 = (unsigned int)(cur2 >> b1) & 1u;
        unsigned int r1, r2;
        if (b1 < 63) {
          r1 = (unsigned int)(cur1 >> (b1+1)) & 1u;
          r2 = (unsigned int)(cur2 >> (b1+1)) & 1u;
        } else {
          r1 = (unsigned int)M[lr][w1+1] & 1u;
          r2 = (w1 < 3) ? ((unsigned int)M[lr][w1+5] & 1u) : 0u;
        }
        unsigned int u1 = 0, u2 = 0;
        if (hasUp) {
          u1 = (unsigned int)(M[lr-1][w1]   >> b1) & 1u;
          u2 = (unsigned int)(M[lr-1][w1+4] >> b1) & 1u;
        }
        if (c1) { aP[li][m] += p1; aP2[li][m] += p1s; }
        if (c2) { aP[li][m] += p2; aP2[li][m] += p2s; }
        if (c1 & r1) aDX[li][m] += d1;
        if (hasR2 && (c2 & r2)) aDX[li][m] += d2;
        if (c1 & u1) aDY[li][m] += v1;
        if (c2 & u2) aDY[li][m] += v2;
      }
    }
    p1_prev = p1; p2_prev = p2;
    __syncthreads();
  }

  // ---- block reduce + f64 atomics ----
  #pragma unroll
  for (int li = 0; li < 3; ++li) {
    #pragma unroll
    for (int m = 0; m < 3; ++m) {
      float s0 = aP[li][m], s1 = aP2[li][m], s2 = aDX[li][m], s3 = aDY[li][m];
      for (int off = 32; off; off >>= 1) {
        s0 += __shfl_down(s0, off);
        s1 += __shfl_down(s1, off);
        s2 += __shfl_down(s2, off);
        s3 += __shfl_down(s3, off);
      }
      if (lane == 0) {
        double* S = sums + (size_t)(b*3 + li)*12;
        atomicAdd(S + 0 + m, (double)s0);
        atomicAdd(S + 3 + m, (double)s1);
        atomicAdd(S + 6 + m, (double)s2);
        atomicAdd(S + 9 + m, (double)s3);
      }
    }
  }
  float va = aAbs;
  for (int off = 32; off; off >>= 1) va += __shfl_down(va, off);
  if (lane == 0) atomicAdd(sumAbs, (double)va);
}

__global__ __launch_bounds__(256) void pass2_kernel(
    const float* __restrict__ pred, const float* __restrict__ img1,
    const float* __restrict__ img2,
    const unsigned long long* __restrict__ mRegG,
    const unsigned long long* __restrict__ mE1G,
    const int* __restrict__ counts,
    float* __restrict__ rankval, int* __restrict__ rankvalid)
{
  const int r = blockIdx.x;       // 0..47
  const int b = r / 3;
  const int t = threadIdx.x;
  __shared__ int rowc[HH];
  __shared__ int pre[HH+1];
  __shared__ int idxArr[200];
  __shared__ float redH[100];
  __shared__ int   redP[100];

  int n_reg = counts[r*9 + 0];
  int n_e1  = counts[r*9 + 1];
  int useE1 = (n_e1 >= 2);
  int n1 = useE1 ? n_e1 : n_reg;
  if (!(n_reg >= 2 && n1 >= 2)) {
    if (t == 0) { rankval[r] = 0.f; rankvalid[r] = 0; }
    return;
  }
  const unsigned long long* M = (useE1 ? mE1G : mRegG) + (size_t)r*HH*8;

  for (int row = t; row < HH; row += 256) {
    int c = 0;
    #pragma unroll
    for (int w = 0; w < 8; ++w) c += __popcll(M[row*8 + w]);
    rowc[row] = c;
  }
  __syncthreads();
  if (t == 0) {
    int s = 0;
    for (int i = 0; i < HH; ++i) { pre[i] = s; s += rowc[i]; }
    pre[HH] = s;
  }
  __syncthreads();

  if (t < 200) {
    unsigned int h = hashu(0x9e3779b9u + (unsigned)(r*200 + t));
    float u = (float)(h >> 8) * (1.0f / 16777216.0f);
    int k = (int)(u * (float)n1);
    if (k >= n1) k = n1 - 1;
    if (k < 0) k = 0;
    int lo = 0, hi = HH;
    while (hi - lo > 1) { int mid = (lo + hi) >> 1; if (pre[mid] <= k) lo = mid; else hi = mid; }
    int row = lo;
    int local = k - pre[row];
    int idx = 0;
    #pragma unroll
    for (int w = 0; w < 8; ++w) {
      unsigned long long mm = M[row*8 + w];
      int c = __popcll(mm);
      if (local < c) {
        for (int i = 0; i < local; ++i) mm &= mm - 1;
        idx = row*WW + w*64 + __builtin_ctzll(mm);
        local = 1 << 20;  // resolved
      } else {
        local -= c;
      }
    }
    idxArr[t] = idx;
  }
  __syncthreads();

  if (t < 100) {
    int ii = idxArr[t], jj = idxArr[t+100];
    size_t base = (size_t)b * HWTOT;
    float pi = pred[base+ii], pj = pred[base+jj];
    float xi = 0.5f*(1.f - img1[base+ii]) + 0.5f*img2[base+ii];
    float xj = 0.5f*(1.f - img1[base+jj]) + 0.5f*img2[base+jj];
    float s = (xi > xj) ? 1.f : ((xi < xj) ? -1.f : 0.f);
    int pv = (ii != jj) && (s != 0.f);
    float hinge = fmaxf(0.f, -(pi - pj)*s);
    redH[t] = pv ? hinge : 0.f;
    redP[t] = pv;
  }
  __syncthreads();
  if (t == 0) {
    float sh = 0.f; int sp = 0;
    for (int i = 0; i < 100; ++i) { sh += redH[i]; sp += redP[i]; }
    rankval[r]   = sh / (float)(sp > 0 ? sp : 1);
    rankvalid[r] = (sp > 0) ? 1 : 0;
  }
}

__global__ __launch_bounds__(64) void pass3_kernel(
    const double* __restrict__ sums, const double* __restrict__ sumAbs,
    const int* __restrict__ counts,
    const float* __restrict__ rankval, const int* __restrict__ rankvalid,
    float* __restrict__ out)
{
  const int t = threadIdx.x;
  __shared__ double svv[NREG]; __shared__ int svd[NREG];
  __shared__ double smv[NREG]; __shared__ int smd[NREG];
  if (t < NREG) {
    int li = t % 3;
    const int* C = counts + t*9;
    const double* S = sums + (size_t)t*12;
    int n_reg = C[0], n_e1 = C[1], n_e2 = C[2];
    int m1 = (n_e1 < 2) ? 0 : 1;
    int m2 = (n_e2 < 3) ? m1 : 2;
    int n2 = C[m2];
    double n2s = (double)(n2 > 1 ? n2 : 1);
    double mu  = S[m2] / n2s;
    double var = S[3+m2] / n2s - mu*mu;
    if (var < 0.0) var = 0.0;
    double cv = sqrt(var) / (fabs(mu) + 1e-6);
    double tcv = (li == 0) ? 0.077 : ((li == 1) ? 0.227 : 0.348);
    svv[t] = fabs(cv - tcv);
    svd[t] = (n_reg >= 3 && n2 >= 3);
    int cx = C[3+m2], cy = C[6+m2];
    double mean_x = S[6+m2] / (double)(cx > 1 ? cx : 1);
    double mean_y = S[9+m2] / (double)(cy > 1 ? cy : 1);
    int hx = (cx > 0), hy = (cy > 0);
    int npres = hx + hy;
    smv[t] = (mean_x*hx + mean_y*hy) / (double)(npres > 1 ? npres : 1);
    smd[t] = (n_reg >= 3 && n2 >= 3 && npres > 0);
  }
  __syncthreads();
  if (t == 0) {
    double s_std = 0, s_sm = 0, s_rk = 0;
    int c_std = 0, c_sm = 0, c_rk = 0;
    for (int i = 0; i < NREG; ++i) {
      if (svd[i])       { s_std += svv[i];     c_std++; }
      if (smd[i])       { s_sm  += smv[i];     c_sm++;  }
      if (rankvalid[i]) { s_rk  += rankval[i]; c_rk++;  }
    }
    double loss_std = c_std ? s_std / c_std : 0.0;
    double loss_sm  = c_sm  ? s_sm  / c_sm  : 0.0;
    double loss_rk  = c_rk  ? s_rk  / c_rk  : 0.0;
    double loss_mean = sumAbs[0] / (double)((long long)BB * HWTOT);
    double total = 0.5*loss_mean + 0.5*loss_std + loss_rk + loss_sm;
    out[0] = (float)total;
  }
}

extern "C" void kernel_launch(void* const* d_in, const int* in_sizes, int n_in,
                              void* d_out, int out_size, void* d_ws, size_t ws_size,
                              hipStream_t stream) {
  const float* pred   = (const float*)d_in[0];
  const float* target = (const float*)d_in[1];
  const int*   lab    = (const int*)d_in[2];
  const float* img1   = (const float*)d_in[3];
  const float* img2   = (const float*)d_in[4];
  float* out = (float*)d_out;
  char* ws = (char*)d_ws;

  double* sums    = (double*)ws;
  double* sumAbs  = (double*)(ws + OFF_SUMABS);
  int*    counts  = (int*)(ws + OFF_COUNTS);
  float*  rankval = (float*)(ws + OFF_RANKV);
  int*    rankvld = (int*)(ws + OFF_RANKD);
  unsigned long long* mReg = (unsigned long long*)(ws + OFF_MREG);
  unsigned long long* mE1  = (unsigned long long*)(ws + OFF_ME1);

  hipMemsetAsync(ws, 0, 8192, stream);

  dim3 g1(NBANDS, BB);
  pass1_kernel<<<g1, 256, 0, stream>>>(pred, target, lab, sums, sumAbs, counts, mReg, mE1);
  pass2_kernel<<<NREG, 256, 0, stream>>>(pred, img1, img2, mReg, mE1, counts, rankval, rankvld);
  pass3_kernel<<<1, 64, 0, stream>>>(sums, sumAbs, counts, rankval, rankvld, out);
}

// Round 2
// 160.061 us; speedup vs baseline: 1.3030x; 1.3030x over previous
//
#include <hip/hip_runtime.h>

#define BB 16
#define HH 512
#define WW 512
#define BH 8
#define NR (BH+5)          // 13 rows incl. halo
#define NBANDS (HH/BH)     // 64
#define NREG 48
#define HWTOT (HH*WW)

// ws layout (bytes):
//   0       double sums[48][12]   (sumP[3], sumP2[3], sdx[3], sdy[3])
//   4608    double sumAbs
//   4616    int counts[48][9]     (cnt[3], cx[3], cy[3])
//   6344    float rankval[48]
//   6536    int rankvalid[48]
//   8192    u64 maskReg[48][512][8]
//   1581056 u64 maskE1 [48][512][8]
#define OFF_SUMABS 4608
#define OFF_COUNTS 4616
#define OFF_RANKV  6344
#define OFF_RANKD  6536
#define OFF_MREG   8192
#define MASKBYTES  (48LL*512*8*8)
#define OFF_ME1    (OFF_MREG + MASKBYTES)

__device__ __forceinline__ unsigned int hashu(unsigned int x) {
  x ^= x >> 16; x *= 0x7feb352dU; x ^= x >> 15; x *= 0x846ca68bU; x ^= x >> 16;
  return x;
}

__global__ __launch_bounds__(256) void pass1_kernel(
    const float* __restrict__ pred, const float* __restrict__ target,
    const int* __restrict__ lab,
    double* __restrict__ sums, double* __restrict__ sumAbs,
    int* __restrict__ counts,
    unsigned long long* __restrict__ mRegG, unsigned long long* __restrict__ mE1G)
{
  __shared__ unsigned long long REG[3][NR][8];
  __shared__ unsigned long long Hh [3][NR][8];
  __shared__ unsigned long long E1v[3][NR][8];
  __shared__ unsigned long long E1H[3][NR][8];
  __shared__ unsigned long long E2v[3][NR][8];
  __shared__ int   Lc[27];
  __shared__ float RED[4][37];

  const int t    = threadIdx.x;
  const int lane = t & 63;
  const int wv   = t >> 6;
  const int r0   = blockIdx.x * BH;
  const int b    = blockIdx.y;
  const int R    = r0 - 3;

  if (t < 27) Lc[t] = 0;

  // ---- build region bitmasks for rows lr 0..NR-1 (gy = R+lr) ----
  for (int lr = 0; lr < NR; ++lr) {
    int gy = R + lr;
    int l1 = -1, l2 = -1;
    if ((unsigned)gy < (unsigned)HH) {
      const int* lp = lab + ((size_t)b*HH + gy)*WW;
      l1 = lp[t]; l2 = lp[t+256];
    }
    unsigned long long m1, m2;
    m1 = __ballot(l1 == 5);  m2 = __ballot(l2 == 5);
    if (lane == 0) { REG[0][lr][wv] = m1; REG[0][lr][wv+4] = m2; }
    m1 = __ballot(l1 == 8);  m2 = __ballot(l2 == 8);
    if (lane == 0) { REG[1][lr][wv] = m1; REG[1][lr][wv+4] = m2; }
    m1 = __ballot(l1 == 13); m2 = __ballot(l2 == 13);
    if (lane == 0) { REG[2][lr][wv] = m1; REG[2][lr][wv+4] = m2; }
  }
  __syncthreads();

  // ---- H-erode all labels ----
  for (int task = t; task < 3*NR*8; task += 256) {
    int w = task & 7, q = task >> 3;
    int lr = q % NR, li = q / NR;
    unsigned long long m  = REG[li][lr][w];
    unsigned long long lm = (m << 1) | (w ? (REG[li][lr][w-1] >> 63) : 1ULL);
    unsigned long long rm = (m >> 1) | ((w < 7) ? (REG[li][lr][w+1] << 63) : (1ULL << 63));
    Hh[li][lr][w] = m & lm & rm;
  }
  __syncthreads();
  // ---- V-erode -> E1 (lr 1..NR-2) ----
  for (int task = t; task < 3*(NR-2)*8; task += 256) {
    int w = task & 7, q = task >> 3;
    int lr = q % (NR-2) + 1, li = q / (NR-2);
    int gy = R + lr;
    unsigned long long v = Hh[li][lr][w];
    if (gy - 1 >= 0) v &= Hh[li][lr-1][w];
    if (gy + 1 < HH) v &= Hh[li][lr+1][w];
    E1v[li][lr][w] = v;
  }
  __syncthreads();
  // ---- H-erode E1 ----
  for (int task = t; task < 3*(NR-2)*8; task += 256) {
    int w = task & 7, q = task >> 3;
    int lr = q % (NR-2) + 1, li = q / (NR-2);
    unsigned long long m  = E1v[li][lr][w];
    unsigned long long lm = (m << 1) | (w ? (E1v[li][lr][w-1] >> 63) : 1ULL);
    unsigned long long rm = (m >> 1) | ((w < 7) ? (E1v[li][lr][w+1] << 63) : (1ULL << 63));
    E1H[li][lr][w] = m & lm & rm;
  }
  __syncthreads();
  // ---- V-erode -> E2 (lr 2..NR-3) ----
  for (int task = t; task < 3*(NR-4)*8; task += 256) {
    int w = task & 7, q = task >> 3;
    int lr = q % (NR-4) + 2, li = q / (NR-4);
    int gy = R + lr;
    unsigned long long v = E1H[li][lr][w];
    if (gy - 1 >= 0) v &= E1H[li][lr-1][w];
    if (gy + 1 < HH) v &= E1H[li][lr+1][w];
    E2v[li][lr][w] = v;
  }
  __syncthreads();

  // ---- write region/e1 row masks for rank sampling ----
  for (int task = t; task < 3*BH*8; task += 256) {
    int w   = task & 7;
    int row = (task >> 3) % BH;
    int li  = task / (BH*8);
    int gy  = r0 + row;
    int lr  = row + 3;
    size_t base = (((size_t)(b*3 + li))*HH + gy)*8 + w;
    mRegG[base] = REG[li][lr][w];
    mE1G[base]  = E1v[li][lr][w];
  }

  // ---- counts via LDS atomics: 9 combos x 64 (row,word) tasks ----
  for (int task = t; task < 9*64; task += 256) {
    int idx = task & 63, combo = task >> 6;
    int li = combo / 3, m = combo % 3;
    int row = idx >> 3, w = idx & 7;
    int lr = row + 3, gy = r0 + row;
    const unsigned long long (*M)[8] = (m == 0) ? REG[li] : ((m == 1) ? E1v[li] : E2v[li]);
    unsigned long long mm = M[lr][w];
    int c = __popcll(mm);
    unsigned long long nx = (w < 7) ? M[lr][w+1] : 0ULL;
    int cx = __popcll(mm & ((mm >> 1) | (nx << 63)));
    int cy = (gy > 0) ? __popcll(mm & M[lr-1][w]) : 0;
    atomicAdd(&Lc[combo*3 + 0], c);
    atomicAdd(&Lc[combo*3 + 1], cx);
    atomicAdd(&Lc[combo*3 + 2], cy);
  }

  // ---- stats: per-thread accumulators over 2 columns (t, t+256) ----
  float aP[9]  = {};
  float aP2[9] = {};
  float aDX[9] = {};
  float aDY[9] = {};
  float aAbs = 0.f;

  const int w1 = wv;
  const int b1 = lane;

  float p1_prev = 0.f, p2_prev = 0.f;
  if (r0 > 0) {
    const float* pr = pred + ((size_t)b*HH + (r0-1))*WW;
    p1_prev = pr[t]; p2_prev = pr[t+256];
  }

  __syncthreads();   // counts LDS atomics done; masks stable (read-only below)

  if (t < 27) {
    int combo = t / 3, stat = t % 3;
    int li = combo / 3, m = combo % 3;
    atomicAdd(counts + (b*3 + li)*9 + stat*3 + m, Lc[t]);
  }

  // init carried "up-row" bits from lr=2 (gy = r0-1)
  unsigned int ub1 = 0, ub2 = 0;
  #pragma unroll
  for (int li = 0; li < 3; ++li) {
    #pragma unroll
    for (int m = 0; m < 3; ++m) {
      const int cb = li*3 + m;
      const unsigned long long (*M)[8] = (m == 0) ? REG[li] : ((m == 1) ? E1v[li] : E2v[li]);
      ub1 |= (((unsigned int)(M[2][w1]   >> b1)) & 1u) << cb;
      ub2 |= (((unsigned int)(M[2][w1+4] >> b1)) & 1u) << cb;
    }
  }

  const bool hasR2 = (t < 255);
  for (int row = 0; row < BH; ++row) {
    int gy = r0 + row;
    int lr = row + 3;
    const float* prow = pred   + ((size_t)b*HH + gy)*WW;
    const float* trow = target + ((size_t)b*HH + gy)*WW;
    float p1 = prow[t], p2 = prow[t+256];
    float pr1 = prow[t+1];
    float pr2 = hasR2 ? prow[t+257] : 0.f;
    float tg1 = trow[t], tg2 = trow[t+256];
    aAbs += fabsf(p1 - tg1) + fabsf(p2 - tg2);
    float d1 = fabsf(pr1 - p1);
    float d2 = fabsf(pr2 - p2);
    float v1 = fabsf(p1 - p1_prev);
    float v2 = fabsf(p2 - p2_prev);
    float p1s = p1*p1, p2s = p2*p2;
    const bool hasUp = (gy > 0);
    unsigned int nb1 = 0, nb2 = 0;
    #pragma unroll
    for (int li = 0; li < 3; ++li) {
      #pragma unroll
      for (int m = 0; m < 3; ++m) {
        const int cb = li*3 + m;
        const unsigned long long (*M)[8] = (m == 0) ? REG[li] : ((m == 1) ? E1v[li] : E2v[li]);
        unsigned long long cur1 = M[lr][w1];
        unsigned long long cur2 = M[lr][w1+4];
        unsigned int c1 = (unsigned int)(cur1 >> b1) & 1u;
        unsigned int c2 = (unsigned int)(cur2 >> b1) & 1u;
        unsigned int r1, r2;
        if (b1 < 63) {
          r1 = (unsigned int)(cur1 >> (b1+1)) & 1u;
          r2 = (unsigned int)(cur2 >> (b1+1)) & 1u;
        } else {
          r1 = (unsigned int)M[lr][w1+1] & 1u;
          r2 = (w1 < 3) ? ((unsigned int)M[lr][w1+5] & 1u) : 0u;
        }
        unsigned int u1 = hasUp ? ((ub1 >> cb) & 1u) : 0u;
        unsigned int u2 = hasUp ? ((ub2 >> cb) & 1u) : 0u;
        if (c1) { aP[cb] += p1; aP2[cb] += p1s; }
        if (c2) { aP[cb] += p2; aP2[cb] += p2s; }
        if (c1 & r1) aDX[cb] += d1;
        if (hasR2 & (bool)(c2 & r2)) aDX[cb] += d2;
        if (c1 & u1) aDY[cb] += v1;
        if (c2 & u2) aDY[cb] += v2;
        nb1 |= c1 << cb;
        nb2 |= c2 << cb;
      }
    }
    ub1 = nb1; ub2 = nb2;
    p1_prev = p1; p2_prev = p2;
  }

  // ---- per-wave shfl reduce, lane0 -> LDS, cross-wave -> f64 atomics ----
  #pragma unroll
  for (int cb = 0; cb < 9; ++cb) {
    float s0 = aP[cb], s1 = aP2[cb], s2 = aDX[cb], s3 = aDY[cb];
    for (int off = 32; off; off >>= 1) {
      s0 += __shfl_down(s0, off);
      s1 += __shfl_down(s1, off);
      s2 += __shfl_down(s2, off);
      s3 += __shfl_down(s3, off);
    }
    if (lane == 0) {
      RED[wv][0*9 + cb] = s0;
      RED[wv][1*9 + cb] = s1;
      RED[wv][2*9 + cb] = s2;
      RED[wv][3*9 + cb] = s3;
    }
  }
  {
    float va = aAbs;
    for (int off = 32; off; off >>= 1) va += __shfl_down(va, off);
    if (lane == 0) RED[wv][36] = va;
  }
  __syncthreads();
  if (t < 37) {
    float s = RED[0][t] + RED[1][t] + RED[2][t] + RED[3][t];
    if (t < 36) {
      int stat = t / 9, cb = t % 9;
      int li = cb / 3, m = cb % 3;
      atomicAdd(sums + (size_t)(b*3 + li)*12 + stat*3 + m, (double)s);
    } else {
      atomicAdd(sumAbs, (double)s);
    }
  }
}

__global__ __launch_bounds__(256) void pass2_kernel(
    const float* __restrict__ pred, const float* __restrict__ img1,
    const float* __restrict__ img2,
    const unsigned long long* __restrict__ mRegG,
    const unsigned long long* __restrict__ mE1G,
    const int* __restrict__ counts,
    float* __restrict__ rankval, int* __restrict__ rankvalid)
{
  const int r = blockIdx.x;       // 0..47
  const int b = r / 3;
  const int t = threadIdx.x;
  __shared__ int rowc[HH];
  __shared__ int pre[HH];
  __shared__ int grpPre[64];
  __shared__ int idxArr[200];
  __shared__ float redH[100];
  __shared__ int   redP[100];

  int n_reg = counts[r*9 + 0];
  int n_e1  = counts[r*9 + 1];
  int useE1 = (n_e1 >= 2);
  int n1 = useE1 ? n_e1 : n_reg;
  if (!(n_reg >= 2 && n1 >= 2)) {
    if (t == 0) { rankval[r] = 0.f; rankvalid[r] = 0; }
    return;
  }
  const unsigned long long* M = (useE1 ? mE1G : mRegG) + (size_t)r*HH*8;

  // coalesced row popcounts: thread t handles rows 2t, 2t+1
  {
    int row = t*2;
    int c0 = 0, c1 = 0;
    #pragma unroll
    for (int w = 0; w < 8; ++w) c0 += __popcll(M[row*8 + w]);
    #pragma unroll
    for (int w = 0; w < 8; ++w) c1 += __popcll(M[(row+1)*8 + w]);
    rowc[row] = c0; rowc[row+1] = c1;
  }
  __syncthreads();
  // parallel prefix: wave 0 scans 64 groups of 8 rows
  if (t < 64) {
    int base = t*8, s = 0;
    #pragma unroll
    for (int k = 0; k < 8; ++k) s += rowc[base + k];
    int v = s;
    for (int off = 1; off < 64; off <<= 1) {
      int o = __shfl_up(v, off);
      if (t >= off) v += o;
    }
    grpPre[t] = v - s;   // exclusive group base
  }
  __syncthreads();
  if (t < 64) {
    int s = grpPre[t];
    int base = t*8;
    #pragma unroll
    for (int k = 0; k < 8; ++k) { pre[base + k] = s; s += rowc[base + k]; }
  }
  __syncthreads();

  if (t < 200) {
    unsigned int h = hashu(0x9e3779b9u + (unsigned)(r*200 + t));
    float u = (float)(h >> 8) * (1.0f / 16777216.0f);
    int k = (int)(u * (float)n1);
    if (k >= n1) k = n1 - 1;
    if (k < 0) k = 0;
    int lo = 0, hi = HH;
    while (hi - lo > 1) { int mid = (lo + hi) >> 1; if (pre[mid] <= k) lo = mid; else hi = mid; }
    int row = lo;
    int local = k - pre[row];
    int idx = 0;
    #pragma unroll
    for (int w = 0; w < 8; ++w) {
      unsigned long long mm = M[row*8 + w];
      int c = __popcll(mm);
      if (local < c) {
        for (int i = 0; i < local; ++i) mm &= mm - 1;
        idx = row*WW + w*64 + __builtin_ctzll(mm);
        local = 1 << 20;  // resolved
      } else {
        local -= c;
      }
    }
    idxArr[t] = idx;
  }
  __syncthreads();

  if (t < 100) {
    int ii = idxArr[t], jj = idxArr[t+100];
    size_t base = (size_t)b * HWTOT;
    float pi = pred[base+ii], pj = pred[base+jj];
    float xi = 0.5f*(1.f - img1[base+ii]) + 0.5f*img2[base+ii];
    float xj = 0.5f*(1.f - img1[base+jj]) + 0.5f*img2[base+jj];
    float s = (xi > xj) ? 1.f : ((xi < xj) ? -1.f : 0.f);
    int pv = (ii != jj) && (s != 0.f);
    float hinge = fmaxf(0.f, -(pi - pj)*s);
    redH[t] = pv ? hinge : 0.f;
    redP[t] = pv;
  }
  __syncthreads();
  if (t == 0) {
    float sh = 0.f; int sp = 0;
    for (int i = 0; i < 100; ++i) { sh += redH[i]; sp += redP[i]; }
    rankval[r]   = sh / (float)(sp > 0 ? sp : 1);
    rankvalid[r] = (sp > 0) ? 1 : 0;
  }
}

__global__ __launch_bounds__(64) void pass3_kernel(
    const double* __restrict__ sums, const double* __restrict__ sumAbs,
    const int* __restrict__ counts,
    const float* __restrict__ rankval, const int* __restrict__ rankvalid,
    float* __restrict__ out)
{
  const int t = threadIdx.x;
  __shared__ double svv[NREG]; __shared__ int svd[NREG];
  __shared__ double smv[NREG]; __shared__ int smd[NREG];
  if (t < NREG) {
    int li = t % 3;
    const int* C = counts + t*9;
    const double* S = sums + (size_t)t*12;
    int n_reg = C[0], n_e1 = C[1], n_e2 = C[2];
    int m1 = (n_e1 < 2) ? 0 : 1;
    int m2 = (n_e2 < 3) ? m1 : 2;
    int n2 = C[m2];
    double n2s = (double)(n2 > 1 ? n2 : 1);
    double mu  = S[m2] / n2s;
    double var = S[3+m2] / n2s - mu*mu;
    if (var < 0.0) var = 0.0;
    double cv = sqrt(var) / (fabs(mu) + 1e-6);
    double tcv = (li == 0) ? 0.077 : ((li == 1) ? 0.227 : 0.348);
    svv[t] = fabs(cv - tcv);
    svd[t] = (n_reg >= 3 && n2 >= 3);
    int cx = C[3+m2], cy = C[6+m2];
    double mean_x = S[6+m2] / (double)(cx > 1 ? cx : 1);
    double mean_y = S[9+m2] / (double)(cy > 1 ? cy : 1);
    int hx = (cx > 0), hy = (cy > 0);
    int npres = hx + hy;
    smv[t] = (mean_x*hx + mean_y*hy) / (double)(npres > 1 ? npres : 1);
    smd[t] = (n_reg >= 3 && n2 >= 3 && npres > 0);
  }
  __syncthreads();
  if (t == 0) {
    double s_std = 0, s_sm = 0, s_rk = 0;
    int c_std = 0, c_sm = 0, c_rk = 0;
    for (int i = 0; i < NREG; ++i) {
      if (svd[i])       { s_std += svv[i];     c_std++; }
      if (smd[i])       { s_sm  += smv[i];     c_sm++;  }
      if (rankvalid[i]) { s_rk  += rankval[i]; c_rk++;  }
    }
    double loss_std = c_std ? s_std / c_std : 0.0;
    double loss_sm  = c_sm  ? s_sm  / c_sm  : 0.0;
    double loss_rk  = c_rk  ? s_rk  / c_rk  : 0.0;
    double loss_mean = sumAbs[0] / (double)((long long)BB * HWTOT);
    double total = 0.5*loss_mean + 0.5*loss_std + loss_rk + loss_sm;
    out[0] = (float)total;
  }
}

extern "C" void kernel_launch(void* const* d_in, const int* in_sizes, int n_in,
                              void* d_out, int out_size, void* d_ws, size_t ws_size,
                              hipStream_t stream) {
  const float* pred   = (const float*)d_in[0];
  const float* target = (const float*)d_in[1];
  const int*   lab    = (const int*)d_in[2];
  const float* img1   = (const float*)d_in[3];
  const float* img2   = (const float*)d_in[4];
  float* out = (float*)d_out;
  char* ws = (char*)d_ws;

  double* sums    = (double*)ws;
  double* sumAbs  = (double*)(ws + OFF_SUMABS);
  int*    counts  = (int*)(ws + OFF_COUNTS);
  float*  rankval = (float*)(ws + OFF_RANKV);
  int*    rankvld = (int*)(ws + OFF_RANKD);
  unsigned long long* mReg = (unsigned long long*)(ws + OFF_MREG);
  unsigned long long* mE1  = (unsigned long long*)(ws + OFF_ME1);

  hipMemsetAsync(ws, 0, 8192, stream);

  dim3 g1(NBANDS, BB);
  pass1_kernel<<<g1, 256, 0, stream>>>(pred, target, lab, sums, sumAbs, counts, mReg, mE1);
  pass2_kernel<<<NREG, 256, 0, stream>>>(pred, img1, img2, mReg, mE1, counts, rankval, rankvld);
  pass3_kernel<<<1, 64, 0, stream>>>(sums, sumAbs, counts, rankval, rankvld, out);
}

// Round 3
// 158.034 us; speedup vs baseline: 1.3198x; 1.0128x over previous
//
#include <hip/hip_runtime.h>

#define BB 16
#define HH 512
#define WW 512
#define BH 16
#define NR (BH+5)          // 21 rows incl. halo
#define NBANDS (HH/BH)     // 32
#define NREG 48
#define HWTOT (HH*WW)
#define MASK21 0x1FFFFFu

// ws layout (bytes):
//   0        double sums[48][12]   (sumP[3], sumP2[3], sdx[3], sdy[3])
//   4608     double sumAbs
//   4616     int counts[48][9]     (cnt[3], cx[3], cy[3])
//   6344     float rankval[48]
//   6536     int rankvalid[48]
//   6728     int ctr
//   8192     int rowcR[48][512]
//   106496   int rowcE[48][512]
//   204800   u64 maskReg[48][512][8]
//   1777664  u64 maskE1 [48][512][8]
#define OFF_SUMABS 4608
#define OFF_COUNTS 4616
#define OFF_RANKV  6344
#define OFF_RANKD  6536
#define OFF_CTR    6728
#define OFF_ROWCR  8192
#define OFF_ROWCE  (OFF_ROWCR + 48*512*4)
#define OFF_MREG   (OFF_ROWCE + 48*512*4)
#define MASKBYTES  (48LL*512*8*8)
#define OFF_ME1    (OFF_MREG + MASKBYTES)

__device__ __forceinline__ unsigned int hashu(unsigned int x) {
  x ^= x >> 16; x *= 0x7feb352dU; x ^= x >> 15; x *= 0x846ca68bU; x ^= x >> 16;
  return x;
}

__global__ __launch_bounds__(512, 4) void pass1_kernel(
    const float* __restrict__ pred, const float* __restrict__ target,
    const int* __restrict__ lab,
    double* __restrict__ sums, double* __restrict__ sumAbs,
    int* __restrict__ counts,
    unsigned long long* __restrict__ mRegG, unsigned long long* __restrict__ mE1G,
    int* __restrict__ rowcR, int* __restrict__ rowcE)
{
  __shared__ unsigned long long XCH[514];   // packed 3x21-bit column masks
  __shared__ unsigned long long NB0[512];   // nbr pack combos 0..3 (16b rows each)
  __shared__ unsigned long long NB1[512];   // combos 4..7
  __shared__ unsigned int      NB2[512];    // combo 8
  __shared__ int   RC[96];                  // rowcnt [type(2)][li(3)][row(16)]
  __shared__ float RED[8][37];
  __shared__ unsigned int CNT[8][14];

  const int t    = threadIdx.x;
  const int lane = t & 63;
  const int wv   = t >> 6;
  const int c    = t;                 // column owned by this thread
  const int r0   = blockIdx.x * BH;
  const int b    = blockIdx.y;
  const int R    = r0 - 3;

  if (t < 96) RC[t] = 0;

  // out-of-image rows (bit lr => gy=R+lr outside [0,HH)); erosion treats them as 1
  unsigned int OOR = 0;
  {
    int topClip = -R;                    // rows lr < topClip are above image
    if (topClip > 0) OOR |= (1u << topClip) - 1u;
    int botStart = HH - R;               // rows lr >= botStart below image
    if (botStart < NR) OOR |= (~0u << botStart) & ((1u << NR) - 1u);
  }

  // ---- build per-column label masks (21 bits) ----
  unsigned int colm0 = 0, colm1 = 0, colm2 = 0;
  for (int lr = 0; lr < NR; ++lr) {
    int gy = R + lr;
    if ((unsigned)gy < (unsigned)HH) {
      int l = lab[((size_t)b*HH + gy)*WW + c];
      colm0 |= (l == 5)  ? (1u << lr) : 0u;
      colm1 |= (l == 8)  ? (1u << lr) : 0u;
      colm2 |= (l == 13) ? (1u << lr) : 0u;
    }
  }

  // ---- erosion 1: pack, exchange, H-erode via u64 AND, V-erode in registers ----
  unsigned long long pk =  (unsigned long long)(colm0 | OOR)
        | ((unsigned long long)(colm1 | OOR) << 21)
        | ((unsigned long long)(colm2 | OOR) << 42);
  XCH[c+1] = pk;
  if (t == 0) { XCH[0] = ~0ull; XCH[513] = ~0ull; }
  __syncthreads();
  unsigned long long hp = pk & XCH[c] & XCH[c+2];
  unsigned int e1a[3];
  #pragma unroll
  for (int li = 0; li < 3; ++li) {
    unsigned int h = (unsigned int)((hp >> (21*li)) & MASK21);
    e1a[li] = h & (h >> 1) & (h << 1);   // valid lr 1..19 (OOR bits carry the 1s)
  }
  __syncthreads();
  // ---- erosion 2 ----
  unsigned long long pk2 =  (unsigned long long)((e1a[0] | OOR) & MASK21)
        | ((unsigned long long)((e1a[1] | OOR) & MASK21) << 21)
        | ((unsigned long long)((e1a[2] | OOR) & MASK21) << 42);
  XCH[c+1] = pk2;
  __syncthreads();
  unsigned long long hp2 = pk2 & XCH[c] & XCH[c+2];
  unsigned int e2a[3];
  #pragma unroll
  for (int li = 0; li < 3; ++li) {
    unsigned int h = (unsigned int)((hp2 >> (21*li)) & MASK21);
    e2a[li] = h & (h >> 1) & (h << 1);   // valid lr 2..18
  }

  // combo order cb = li*3 + m, m: 0=REG 1=E1 2=E2
  unsigned int mS[9] = { colm0, e1a[0], e2a[0],
                         colm1, e1a[1], e2a[1],
                         colm2, e1a[2], e2a[2] };

  // ---- neighbor exchange: 16-bit row windows (lr 3..18) per combo ----
  {
    unsigned long long p0 = 0, p1 = 0;
    #pragma unroll
    for (int cb = 0; cb < 4; ++cb) p0 |= (unsigned long long)((mS[cb] >> 3) & 0xFFFFu) << (cb*16);
    #pragma unroll
    for (int cb = 4; cb < 8; ++cb) p1 |= (unsigned long long)((mS[cb] >> 3) & 0xFFFFu) << ((cb-4)*16);
    NB0[c] = p0; NB1[c] = p1; NB2[c] = (mS[8] >> 3) & 0xFFFFu;
  }
  __syncthreads();
  unsigned long long nb0 = (c < 511) ? NB0[c+1] : 0ull;
  unsigned long long nb1 = (c < 511) ? NB1[c+1] : 0ull;
  unsigned int       nb2 = (c < 511) ? NB2[c+1] : 0u;

  // ---- counts (cnt, cx, cy) packed 2x16-bit per u32, wave shfl reduce ----
  {
    unsigned int pkc[14];
    #pragma unroll
    for (int j = 0; j < 14; ++j) pkc[j] = 0;
    #pragma unroll
    for (int cb = 0; cb < 9; ++cb) {
      unsigned int w16 = (mS[cb] >> 3) & 0xFFFFu;
      unsigned int nbw;
      if (cb < 4)      nbw = (unsigned int)(nb0 >> (cb*16)) & 0xFFFFu;
      else if (cb < 8) nbw = (unsigned int)(nb1 >> ((cb-4)*16)) & 0xFFFFu;
      else             nbw = nb2 & 0xFFFFu;
      unsigned int mcl = mS[cb] & ~OOR;
      unsigned int q   = mcl & (mcl << 1);        // bit lr: rows lr-1,lr both set
      unsigned int cnt = __popc(w16);
      unsigned int cx  = __popc(w16 & nbw);
      unsigned int cy  = __popc((q >> 3) & 0xFFFFu);
      int k0 = cb*3;
      pkc[(k0  )>>1] |= cnt << (((k0  )&1)*16);
      pkc[(k0+1)>>1] |= cx  << (((k0+1)&1)*16);
      pkc[(k0+2)>>1] |= cy  << (((k0+2)&1)*16);
    }
    #pragma unroll
    for (int j = 0; j < 14; ++j) {
      unsigned int v = pkc[j];
      for (int off = 32; off; off >>= 1) v += __shfl_down(v, off);
      if (lane == 0) CNT[wv][j] = v;
    }
  }

  // ---- ballots: write sampling masks + per-row popcounts ----
  for (int row = 0; row < BH; ++row) {
    int lr = row + 3, gy = r0 + row;
    #pragma unroll
    for (int li = 0; li < 3; ++li) {
      unsigned long long wR = __ballot((mS[li*3]   >> lr) & 1u);
      unsigned long long wE = __ballot((mS[li*3+1] >> lr) & 1u);
      if (lane == 0) {
        size_t base = (((size_t)(b*3 + li))*HH + gy)*8 + wv;
        mRegG[base] = wR; mE1G[base] = wE;
        atomicAdd(&RC[     li*BH + row], (int)__popcll(wR));
        atomicAdd(&RC[48 + li*BH + row], (int)__popcll(wE));
      }
    }
  }

  // ---- stats row loop: pure register bit extraction ----
  float aP[9] = {}, aP2[9] = {}, aDX[9] = {}, aDY[9] = {};
  float aAbs = 0.f;
  const float* pB = pred   + (size_t)b*HH*WW;
  const float* tB = target + (size_t)b*HH*WW;
  float p_prev = (r0 > 0) ? pB[(size_t)(r0-1)*WW + c] : 0.f;
  const int cR = (c < 511) ? c + 1 : c;   // value irrelevant at c=511 (nbr bits 0)

  #pragma unroll
  for (int row = 0; row < BH; ++row) {
    const int lr = row + 3, gy = r0 + row;
    const float* prow = pB + (size_t)gy*WW;
    float p  = prow[c];
    float pr = prow[cR];
    float tg = tB[(size_t)gy*WW + c];
    aAbs += fabsf(p - tg);
    float d = fabsf(pr - p);
    float v = (gy > 0) ? fabsf(p - p_prev) : 0.f;
    #pragma unroll
    for (int cb = 0; cb < 9; ++cb) {
      unsigned int cur = mS[cb];
      unsigned int c1 = (cur >> lr) & 1u;
      unsigned int u1 = (cur >> (lr-1)) & 1u;
      unsigned int r1;
      if (cb < 4)      r1 = (unsigned int)(nb0 >> (cb*16 + row)) & 1u;
      else if (cb < 8) r1 = (unsigned int)(nb1 >> ((cb-4)*16 + row)) & 1u;
      else             r1 = (nb2 >> row) & 1u;
      float f = c1 ? p : 0.f;
      aP[cb]  += f;
      aP2[cb]  = fmaf(f, p, aP2[cb]);
      aDX[cb] += (c1 & r1) ? d : 0.f;
      aDY[cb] += (c1 & u1) ? v : 0.f;
    }
    p_prev = p;
  }

  // ---- wave reduce floats -> LDS ----
  #pragma unroll
  for (int cb = 0; cb < 9; ++cb) {
    float s0 = aP[cb], s1 = aP2[cb], s2 = aDX[cb], s3 = aDY[cb];
    for (int off = 32; off; off >>= 1) {
      s0 += __shfl_down(s0, off);
      s1 += __shfl_down(s1, off);
      s2 += __shfl_down(s2, off);
      s3 += __shfl_down(s3, off);
    }
    if (lane == 0) {
      RED[wv][0*9 + cb] = s0; RED[wv][1*9 + cb] = s1;
      RED[wv][2*9 + cb] = s2; RED[wv][3*9 + cb] = s3;
    }
  }
  {
    float va = aAbs;
    for (int off = 32; off; off >>= 1) va += __shfl_down(va, off);
    if (lane == 0) RED[wv][36] = va;
  }
  __syncthreads();

  // ---- final outputs ----
  if (t < 37) {
    float s = 0.f;
    #pragma unroll
    for (int w = 0; w < 8; ++w) s += RED[w][t];
    if (t < 36) {
      int stat = t / 9, cb = t % 9, li = cb / 3, m = cb % 3;
      atomicAdd(sums + (size_t)(b*3 + li)*12 + stat*3 + m, (double)s);
    } else {
      atomicAdd(sumAbs, (double)s);
    }
  }
  if (t < 14) {
    unsigned int s = 0;
    #pragma unroll
    for (int w = 0; w < 8; ++w) s += CNT[w][t];
    int k0 = t*2;
    #pragma unroll
    for (int h = 0; h < 2; ++h) {
      int k = k0 + h;
      if (k < 27) {
        unsigned int val = (s >> (h*16)) & 0xFFFFu;
        int cb = k / 3, stat = k % 3, li = cb / 3, m = cb % 3;
        atomicAdd(counts + (b*3 + li)*9 + stat*3 + m, (int)val);
      }
    }
  }
  if (t < 96) {
    int type = t / 48, rem = t % 48;
    int li = rem / BH, row = rem % BH, gy = r0 + row;
    int* dst = type ? rowcE : rowcR;
    dst[((size_t)(b*3 + li))*HH + gy] = RC[t];
  }
}

__global__ __launch_bounds__(256) void pass2_kernel(
    const float* __restrict__ pred, const float* __restrict__ img1,
    const float* __restrict__ img2,
    const unsigned long long* __restrict__ mRegG,
    const unsigned long long* __restrict__ mE1G,
    const int* __restrict__ rowcR, const int* __restrict__ rowcE,
    const int* __restrict__ counts,
    const double* __restrict__ sums, const double* __restrict__ sumAbs,
    float* __restrict__ rankval, int* __restrict__ rankvalid,
    int* __restrict__ ctr, float* __restrict__ out)
{
  const int r = blockIdx.x;       // 0..47
  const int b = r / 3;
  const int t = threadIdx.x;
  const int lane = t & 63;
  const int wv   = t >> 6;
  __shared__ int rowc[HH];
  __shared__ int pre[HH];
  __shared__ int grpPre[64];
  __shared__ int idxArr[200];
  __shared__ float redH[4];
  __shared__ int   redP[4];
  __shared__ int lastFlag;
  __shared__ double svvS[NREG], smvS[NREG];
  __shared__ int svdS[NREG], smdS[NREG];
  __shared__ float rkvS[NREG];
  __shared__ int   rkdS[NREG];

  int n_reg = counts[r*9 + 0];
  int n_e1  = counts[r*9 + 1];
  int useE1 = (n_e1 >= 2);
  int n1 = useE1 ? n_e1 : n_reg;
  bool doRank = (n_reg >= 2 && n1 >= 2);
  float rv = 0.f; int rvd = 0;

  if (doRank) {
    const int* rc = (useE1 ? rowcE : rowcR) + (size_t)r*HH;
    { int2 vv = ((const int2*)rc)[t]; rowc[2*t] = vv.x; rowc[2*t+1] = vv.y; }
    __syncthreads();
    if (t < 64) {
      int base = t*8, s = 0;
      #pragma unroll
      for (int k = 0; k < 8; ++k) s += rowc[base + k];
      int v = s;
      for (int off = 1; off < 64; off <<= 1) {
        int o = __shfl_up(v, off);
        if (t >= off) v += o;
      }
      grpPre[t] = v - s;
    }
    __syncthreads();
    if (t < 64) {
      int s = grpPre[t], base = t*8;
      #pragma unroll
      for (int k = 0; k < 8; ++k) { pre[base + k] = s; s += rowc[base + k]; }
    }
    __syncthreads();

    const unsigned long long* M = (useE1 ? mE1G : mRegG) + (size_t)r*HH*8;
    if (t < 200) {
      unsigned int h = hashu(0x9e3779b9u + (unsigned)(r*200 + t));
      float u = (float)(h >> 8) * (1.0f / 16777216.0f);
      int k = (int)(u * (float)n1);
      if (k >= n1) k = n1 - 1;
      if (k < 0) k = 0;
      int lo = 0, hi = HH;
      while (hi - lo > 1) { int mid = (lo + hi) >> 1; if (pre[mid] <= k) lo = mid; else hi = mid; }
      int row = lo;
      int local = k - pre[row];
      int idx = 0;
      #pragma unroll
      for (int w = 0; w < 8; ++w) {
        unsigned long long mm = M[row*8 + w];
        int cc = __popcll(mm);
        if (local < cc) {
          for (int i = 0; i < local; ++i) mm &= mm - 1;
          idx = row*WW + w*64 + __builtin_ctzll(mm);
          local = 1 << 20;
        } else {
          local -= cc;
        }
      }
      idxArr[t] = idx;
    }
    __syncthreads();

    float hv = 0.f; int pv = 0;
    if (t < 100) {
      int ii = idxArr[t], jj = idxArr[t+100];
      size_t base = (size_t)b * HWTOT;
      float pi = pred[base+ii], pj = pred[base+jj];
      float xi = 0.5f*(1.f - img1[base+ii]) + 0.5f*img2[base+ii];
      float xj = 0.5f*(1.f - img1[base+jj]) + 0.5f*img2[base+jj];
      float s = (xi > xj) ? 1.f : ((xi < xj) ? -1.f : 0.f);
      pv = (ii != jj) && (s != 0.f);
      float hinge = fmaxf(0.f, -(pi - pj)*s);
      hv = pv ? hinge : 0.f;
    }
    for (int off = 32; off; off >>= 1) {
      hv += __shfl_down(hv, off);
      pv += __shfl_down(pv, off);
    }
    if (lane == 0) { redH[wv] = hv; redP[wv] = pv; }
    __syncthreads();
    if (t == 0) {
      float sh = redH[0] + redH[1] + redH[2] + redH[3];
      int   sp = redP[0] + redP[1] + redP[2] + redP[3];
      rv  = sh / (float)(sp > 0 ? sp : 1);
      rvd = (sp > 0) ? 1 : 0;
    }
  }

  if (t == 0) {
    atomicExch(&rankval[r], rv);
    atomicExch(&rankvalid[r], rvd);
    __threadfence();
    int old = atomicAdd(ctr, 1);
    lastFlag = (old == NREG - 1);
  }
  __syncthreads();

  if (lastFlag) {
    __threadfence();   // acquire on each participating thread
    if (t < NREG) {
      int li = t % 3;
      const int* C = counts + t*9;
      const double* S = sums + (size_t)t*12;
      int nr = C[0], ne1 = C[1], ne2 = C[2];
      int m1 = (ne1 < 2) ? 0 : 1;
      int m2 = (ne2 < 3) ? m1 : 2;
      int n2 = C[m2];
      double n2s = (double)(n2 > 1 ? n2 : 1);
      double mu  = S[m2] / n2s;
      double var = S[3+m2] / n2s - mu*mu;
      if (var < 0.0) var = 0.0;
      double cv = sqrt(var) / (fabs(mu) + 1e-6);
      double tcv = (li == 0) ? 0.077 : ((li == 1) ? 0.227 : 0.348);
      svvS[t] = fabs(cv - tcv);
      svdS[t] = (nr >= 3 && n2 >= 3);
      int cx = C[3+m2], cy = C[6+m2];
      double mean_x = S[6+m2] / (double)(cx > 1 ? cx : 1);
      double mean_y = S[9+m2] / (double)(cy > 1 ? cy : 1);
      int hx = (cx > 0), hy = (cy > 0);
      int npres = hx + hy;
      smvS[t] = (mean_x*hx + mean_y*hy) / (double)(npres > 1 ? npres : 1);
      smdS[t] = (nr >= 3 && n2 >= 3 && npres > 0);
      rkvS[t] = rankval[t];
      rkdS[t] = rankvalid[t];
    }
    __syncthreads();
    if (t == 0) {
      double s_std = 0, s_sm = 0, s_rk = 0;
      int c_std = 0, c_sm = 0, c_rk = 0;
      for (int i = 0; i < NREG; ++i) {
        if (svdS[i]) { s_std += svvS[i]; c_std++; }
        if (smdS[i]) { s_sm  += smvS[i]; c_sm++;  }
        if (rkdS[i]) { s_rk  += rkvS[i]; c_rk++;  }
      }
      double loss_std = c_std ? s_std / c_std : 0.0;
      double loss_sm  = c_sm  ? s_sm  / c_sm  : 0.0;
      double loss_rk  = c_rk  ? s_rk  / c_rk  : 0.0;
      double loss_mean = sumAbs[0] / (double)((long long)BB * HWTOT);
      double total = 0.5*loss_mean + 0.5*loss_std + loss_rk + loss_sm;
      out[0] = (float)total;
    }
  }
}

extern "C" void kernel_launch(void* const* d_in, const int* in_sizes, int n_in,
                              void* d_out, int out_size, void* d_ws, size_t ws_size,
                              hipStream_t stream) {
  const float* pred   = (const float*)d_in[0];
  const float* target = (const float*)d_in[1];
  const int*   lab    = (const int*)d_in[2];
  const float* img1   = (const float*)d_in[3];
  const float* img2   = (const float*)d_in[4];
  float* out = (float*)d_out;
  char* ws = (char*)d_ws;

  double* sums    = (double*)ws;
  double* sumAbs  = (double*)(ws + OFF_SUMABS);
  int*    counts  = (int*)(ws + OFF_COUNTS);
  float*  rankval = (float*)(ws + OFF_RANKV);
  int*    rankvld = (int*)(ws + OFF_RANKD);
  int*    ctr     = (int*)(ws + OFF_CTR);
  int*    rowcR   = (int*)(ws + OFF_ROWCR);
  int*    rowcE   = (int*)(ws + OFF_ROWCE);
  unsigned long long* mReg = (unsigned long long*)(ws + OFF_MREG);
  unsigned long long* mE1  = (unsigned long long*)(ws + OFF_ME1);

  hipMemsetAsync(ws, 0, 8192, stream);

  dim3 g1(NBANDS, BB);
  pass1_kernel<<<g1, 512, 0, stream>>>(pred, target, lab, sums, sumAbs, counts,
                                       mReg, mE1, rowcR, rowcE);
  pass2_kernel<<<NREG, 256, 0, stream>>>(pred, img1, img2, mReg, mE1, rowcR, rowcE,
                                         counts, sums, sumAbs, rankval, rankvld, ctr, out);
}